// Round 5
// baseline (204.352 us; speedup 1.0000x reference)
//
#include <hip/hip_runtime.h>
#include <math.h>

#define N_NODES 4096
#define DIM 256
#define NH 4
#define HD 64
#define NG 16
#define LN_EPS 1e-5f
#define TEMP 5.0f
#define RSLACK 4160     // 4096 + 64 rows of slack for tile tails
#define PS_STRIDE 72    // bf16 elems; 144 B row stride, 2-way-aliasing only (free)
#define QT_MAX 24       // 24*16 = 384 max rows/graph
#define KC_MAX 6        // 6*64  = 384 max keys/graph
#define WPG (KC_MAX * QT_MAX * NH)  // 576 wave-works per graph
#define ATTN_BLOCKS (NG * WPG / 4)  // 2304

typedef __attribute__((ext_vector_type(8))) short short8;
typedef __attribute__((ext_vector_type(4))) short short4_t;
typedef __attribute__((ext_vector_type(4))) float f32x4;

__device__ __forceinline__ unsigned short f2bf(float f) {
    unsigned u = __builtin_bit_cast(unsigned, f);
    u += 0x7FFFu + ((u >> 16) & 1u);  // RNE
    return (unsigned short)(u >> 16);
}
__device__ __forceinline__ float bf2f(unsigned short u) {
    return __builtin_bit_cast(float, (unsigned)u << 16);
}
__device__ __forceinline__ float fsigmoid(float z) { return 1.f / (1.f + __expf(-z)); }
__device__ __forceinline__ float ftanh(float z) {
    float t = __expf(2.f * z);
    return (t - 1.f) / (t + 1.f);
}
__device__ __forceinline__ int seg_search(const int* __restrict__ batch, int g) {
    int lo = 0, hi = N_NODES;
    while (lo < hi) {
        int mid = (lo + hi) >> 1;
        if (batch[mid] < g) lo = mid + 1; else hi = mid;
    }
    return lo;
}

// ================= K1: prep (W transpose, x cast, segmax+gcw, seg) ===========
// blocks [0,352): W transpose; [352,1376): x cast; [1376,1392): segmax+gcw;
// 1392: seg array
__global__ __launch_bounds__(256) void prep_kernel(
    const float* __restrict__ x, const float* __restrict__ Wq,
    const float* __restrict__ Wk, const float* __restrict__ Wv,
    const float* __restrict__ Wv1, const float* __restrict__ Wc1,
    const int* __restrict__ batch,
    unsigned short* __restrict__ xb, unsigned short* __restrict__ WqT,
    unsigned short* __restrict__ WkT, unsigned short* __restrict__ WvT,
    unsigned short* __restrict__ Wv1T, unsigned short* __restrict__ Wc1T,
    float* __restrict__ gcw, int* __restrict__ seg) {
    int id = blockIdx.x, tid = threadIdx.x;
    if (id == 1392) {
        if (tid <= NG) seg[tid] = seg_search(batch, tid);
        return;
    }
    if (id >= 1376) {  // segmax + gcw for graph g
        int g = id - 1376;
        __shared__ int sseg[2];
        __shared__ float gl[256];
        if (tid < 2) sseg[tid] = seg_search(batch, g + tid);
        __syncthreads();
        int s = sseg[0], e = sseg[1];
        float m = -INFINITY;
        for (int i = s; i < e; ++i) m = fmaxf(m, x[(size_t)i * DIM + tid]);
        unsigned short mb = f2bf(m);
        gl[tid] = bf2f(mb);  // bf16-rounded, consistent with x cast precision
        __syncthreads();
        float sum = 0.f;
        for (int k = 0; k < 256; ++k)
            sum += gl[k] * Wc1[(size_t)(256 + k) * 256 + tid];
        gcw[g * 256 + tid] = sum;
        return;
    }
    if (id >= 352) {  // x cast
        int base = (id - 352) * 1024 + tid * 4;
        float4 v = *(const float4*)&x[base];
        short4_t o = {(short)f2bf(v.x), (short)f2bf(v.y), (short)f2bf(v.z), (short)f2bf(v.w)};
        *(short4_t*)&xb[base] = o;
        return;
    }
    const float* src; unsigned short* dst; int K, Nn, tX, rel;
    if (id < 64)       { src = Wq;  dst = WqT;  K = 256; Nn = 256; rel = id;      tX = 8;  }
    else if (id < 128) { src = Wk;  dst = WkT;  K = 256; Nn = 256; rel = id-64;   tX = 8;  }
    else if (id < 192) { src = Wv;  dst = WvT;  K = 256; Nn = 256; rel = id-128;  tX = 8;  }
    else if (id < 224) { src = Wv1; dst = Wv1T; K = 256; Nn = 128; rel = id-192;  tX = 8;  }
    else               { src = Wc1; dst = Wc1T; K = 512; Nn = 256; rel = id-224;  tX = 16; }
    int k0 = (rel % tX) * 32, n0 = (rel / tX) * 32;
    __shared__ float t[32][33];
    int c = tid & 31, r0 = tid >> 5;
#pragma unroll
    for (int p = 0; p < 4; ++p) {
        int rr = p * 8 + r0;
        t[rr][c] = src[(size_t)(k0 + rr) * Nn + n0 + c];
    }
    __syncthreads();
#pragma unroll
    for (int p = 0; p < 4; ++p) {
        int rr = p * 8 + r0;
        dst[(size_t)(n0 + rr) * K + k0 + c] = f2bf(t[c][rr]);
    }
}

// ================= K2: MFMA projections ======================================
// z=0 Qb, 1 Kb, 2 Vt (transposed), 3 Tb = tanh(x@Wc1_top + bc1 + gcw[b]) bf16,
// 4 Hvb = relu(x@Wv1+bv1) bf16 (Nc=128)
__global__ __launch_bounds__(256) void gemm_kernel(
    const unsigned short* __restrict__ xb,
    const unsigned short* __restrict__ WqT, const unsigned short* __restrict__ WkT,
    const unsigned short* __restrict__ WvT, const unsigned short* __restrict__ Wv1T,
    const unsigned short* __restrict__ Wc1T,
    const float* __restrict__ bq, const float* __restrict__ bk,
    const float* __restrict__ bv, const float* __restrict__ bv1,
    const float* __restrict__ bc1, const float* __restrict__ gcw,
    const int* __restrict__ batch,
    unsigned short* __restrict__ Qb, unsigned short* __restrict__ Kb,
    unsigned short* __restrict__ Vt, unsigned short* __restrict__ Tb,
    unsigned short* __restrict__ Hvb) {
    int z = blockIdx.z;
    const unsigned short* WT;
    const float* bias;
    int wstride = 256;
    switch (z) {
        case 0: WT = WqT; bias = bq; break;
        case 1: WT = WkT; bias = bk; break;
        case 2: WT = WvT; bias = bv; break;
        case 3: WT = Wc1T; bias = bc1; wstride = 512; break;
        default: WT = Wv1T; bias = bv1; break;
    }
    int ntn = (z == 4) ? 2 : 4;
    int nt0 = blockIdx.y * ntn;
    int tid = threadIdx.x;
    int w = tid >> 6, lane = tid & 63, m = lane & 15, quad = lane >> 4;
    int bm = blockIdx.x * 64;
    int rowA = bm + 16 * w + m;
    short8 a[8];
#pragma unroll
    for (int ks = 0; ks < 8; ++ks)
        a[ks] = *(const short8*)&xb[(size_t)rowA * 256 + ks * 32 + quad * 8];
    int node0 = bm + 16 * w + quad * 4;
    int b4[4];
    if (z == 3) {
#pragma unroll
        for (int r = 0; r < 4; ++r) b4[r] = batch[node0 + r];
    }
    for (int nti = 0; nti < ntn; ++nti) {
        int nt = nt0 + nti;
        f32x4 acc = {0.f, 0.f, 0.f, 0.f};
#pragma unroll
        for (int ks = 0; ks < 8; ++ks) {
            short8 b = *(const short8*)&WT[(size_t)(nt * 16 + m) * wstride + ks * 32 + quad * 8];
            acc = __builtin_amdgcn_mfma_f32_16x16x32_bf16(a[ks], b, acc, 0, 0, 0);
        }
        int col = nt * 16 + m;
        float bb = bias[col];
        if (z == 0) {
#pragma unroll
            for (int r = 0; r < 4; ++r) Qb[(size_t)(node0 + r) * 256 + col] = f2bf(acc[r] + bb);
        } else if (z == 1) {
#pragma unroll
            for (int r = 0; r < 4; ++r) Kb[(size_t)(node0 + r) * 256 + col] = f2bf(acc[r] + bb);
        } else if (z == 2) {
            short4_t pk = {(short)f2bf(acc[0] + bb), (short)f2bf(acc[1] + bb),
                           (short)f2bf(acc[2] + bb), (short)f2bf(acc[3] + bb)};
            *(short4_t*)&Vt[(size_t)col * RSLACK + node0] = pk;
        } else if (z == 3) {
#pragma unroll
            for (int r = 0; r < 4; ++r)
                Tb[(size_t)(node0 + r) * 256 + col] =
                    f2bf(ftanh(acc[r] + bb + gcw[b4[r] * 256 + col]));
        } else {
#pragma unroll
            for (int r = 0; r < 4; ++r)
                Hvb[(size_t)(node0 + r) * 128 + col] = f2bf(fmaxf(acc[r] + bb, 0.f));
        }
    }
}

// ================= K3: attn partials + w =====================================
// blocks [0, 2304): key-split attention partials; [2304, 3328): w rows
__global__ __launch_bounds__(256) void attn_w_kernel(
    const unsigned short* __restrict__ Qb, const unsigned short* __restrict__ Kb,
    const unsigned short* __restrict__ Vt, const int* __restrict__ seg,
    const unsigned short* __restrict__ Hvb, const unsigned short* __restrict__ Tb,
    const float* __restrict__ Wv2, const float* __restrict__ bv2,
    const float* __restrict__ Wc2, const float* __restrict__ bc2,
    unsigned short* __restrict__ Opart, float* __restrict__ Lpart,
    float* __restrict__ wout) {
    int tid = threadIdx.x;
    int w = tid >> 6, lane = tid & 63, m = lane & 15, quad = lane >> 4;
    if (blockIdx.x >= ATTN_BLOCKS) {
        // ---- w rows ----
        int row = (blockIdx.x - ATTN_BLOCKS) * 4 + w;
        ushort2 hv = *(const ushort2*)&Hvb[(size_t)row * 128 + lane * 2];
        float v = bf2f(hv.x) * Wv2[lane * 2] + bf2f(hv.y) * Wv2[lane * 2 + 1];
        short4_t tv = *(const short4_t*)&Tb[(size_t)row * 256 + lane * 4];
        float c = 0.f;
#pragma unroll
        for (int j = 0; j < 4; ++j)
            c += bf2f((unsigned short)tv[j]) * Wc2[lane * 4 + j];
#pragma unroll
        for (int mm = 32; mm; mm >>= 1) {
            v += __shfl_xor(v, mm);
            c += __shfl_xor(c, mm);
        }
        if (lane == 0)
            wout[row] = 0.6f * fsigmoid(v + bv2[0]) + 0.3f * fsigmoid(c + bc2[0]) +
                        0.1f / 4096.f;
        return;
    }
    // ---- attention partial: wave-work (g, kc, qt, h) ----
    __shared__ unsigned short Ps[4 * 16 * PS_STRIDE];
    int wid = blockIdx.x * 4 + w;
    int g = wid / WPG;
    int r1 = wid - g * WPG;
    int kc = r1 / (QT_MAX * NH);
    int r2 = r1 - kc * (QT_MAX * NH);
    int qt = r2 >> 2, h = r2 & 3;
    int s = seg[g], e = seg[g + 1];
    int q0 = s + qt * 16;
    int k0 = s + kc * 64;
    if (q0 >= e || k0 >= e) return;

    short8 qa0 = *(const short8*)&Qb[(size_t)(q0 + m) * 256 + h * 64 + quad * 8];
    short8 qa1 = *(const short8*)&Qb[(size_t)(q0 + m) * 256 + h * 64 + 32 + quad * 8];

    f32x4 S[4];
#pragma unroll
    for (int nt = 0; nt < 4; ++nt) {
        int key = k0 + nt * 16 + m;
        short8 kb0 = *(const short8*)&Kb[(size_t)key * 256 + h * 64 + quad * 8];
        short8 kb1 = *(const short8*)&Kb[(size_t)key * 256 + h * 64 + 32 + quad * 8];
        f32x4 sa = {0.f, 0.f, 0.f, 0.f};
        sa = __builtin_amdgcn_mfma_f32_16x16x32_bf16(qa0, kb0, sa, 0, 0, 0);
        sa = __builtin_amdgcn_mfma_f32_16x16x32_bf16(qa1, kb1, sa, 0, 0, 0);
        S[nt] = sa;
    }
    int wbase = w * 16 * PS_STRIDE;
#pragma unroll
    for (int nt = 0; nt < 4; ++nt) {
        bool valid = (k0 + nt * 16 + m) < e;
#pragma unroll
        for (int r = 0; r < 4; ++r) {
            float p = valid ? __expf(S[nt][r] * 0.125f) : 0.f;
            Ps[wbase + (quad * 4 + r) * PS_STRIDE + nt * 16 + m] = f2bf(p);
        }
    }
    __builtin_amdgcn_wave_barrier();  // order LDS write->read (in-order DS pipe)
    short8 pa0 = *(const short8*)&Ps[wbase + m * PS_STRIDE + quad * 8];
    short8 pa1 = *(const short8*)&Ps[wbase + m * PS_STRIDE + 32 + quad * 8];

    short8 ones = {16256, 16256, 16256, 16256, 16256, 16256, 16256, 16256};  // bf16 1.0
    f32x4 Lacc = {0.f, 0.f, 0.f, 0.f};
    Lacc = __builtin_amdgcn_mfma_f32_16x16x32_bf16(pa0, ones, Lacc, 0, 0, 0);
    Lacc = __builtin_amdgcn_mfma_f32_16x16x32_bf16(pa1, ones, Lacc, 0, 0, 0);
    f32x4 O[4];
#pragma unroll
    for (int nt = 0; nt < 4; ++nt) {
        const unsigned short* vrow = &Vt[(size_t)(h * 64 + nt * 16 + m) * RSLACK + k0];
        short8 vb0 = *(const short8*)&vrow[quad * 8];
        short8 vb1 = *(const short8*)&vrow[32 + quad * 8];
        f32x4 oa = {0.f, 0.f, 0.f, 0.f};
        oa = __builtin_amdgcn_mfma_f32_16x16x32_bf16(pa0, vb0, oa, 0, 0, 0);
        oa = __builtin_amdgcn_mfma_f32_16x16x32_bf16(pa1, vb1, oa, 0, 0, 0);
        O[nt] = oa;
    }
#pragma unroll
    for (int r = 0; r < 4; ++r) {
        int q = q0 + quad * 4 + r;
        if (q < e) {
            if (m == 0) Lpart[((size_t)kc * N_NODES + q) * 4 + h] = Lacc[r];
#pragma unroll
            for (int nt = 0; nt < 4; ++nt)
                Opart[((size_t)kc * N_NODES + q) * 256 + h * 64 + nt * 16 + m] =
                    f2bf(O[nt][r]);
        }
    }
}

// ================= K4: att softmax + combine + residual + LayerNorm ==========
__global__ __launch_bounds__(256) void combine_ln_kernel(
    const unsigned short* __restrict__ Opart, const float* __restrict__ Lpart,
    const float* __restrict__ x, const float* __restrict__ w,
    const float* __restrict__ gamma, const float* __restrict__ beta,
    const int* __restrict__ batch, const int* __restrict__ seg,
    float* __restrict__ out, float* __restrict__ att_out) {
    int n = blockIdx.x;
    int tid = threadIdx.x;
    int g = batch[n];
    int s = seg[g], e = seg[g + 1];
    __shared__ float r1[4], r2[4];
    // per-graph softmax of w*TEMP, recomputed per block (<=384 vals, L2-hot)
    float w1 = (s + tid < e) ? w[s + tid] * TEMP : -1e30f;
    float w2 = (s + 256 + tid < e) ? w[s + 256 + tid] * TEMP : -1e30f;
    float mx = fmaxf(w1, w2);
#pragma unroll
    for (int k2 = 32; k2; k2 >>= 1) mx = fmaxf(mx, __shfl_xor(mx, k2));
    if ((tid & 63) == 0) r1[tid >> 6] = mx;
    __syncthreads();
    float m = fmaxf(fmaxf(r1[0], r1[1]), fmaxf(r1[2], r1[3]));
    float sm = ((s + tid < e) ? __expf(w1 - m) : 0.f) +
               ((s + 256 + tid < e) ? __expf(w2 - m) : 0.f);
#pragma unroll
    for (int k2 = 32; k2; k2 >>= 1) sm += __shfl_xor(sm, k2);
    __syncthreads();  // r1 reuse below needs all reads done (m computed)
    if ((tid & 63) == 0) r2[tid >> 6] = sm;
    __syncthreads();
    float ssum = r2[0] + r2[1] + r2[2] + r2[3];
    float att_n = __expf(w[n] * TEMP - m) / ssum;
    if (tid == 0) att_out[n] = att_n;
    // combine key-chunk partials
    int h = tid >> 6;
    float L = 0.f, O = 0.f;
    for (int c = 0; c < KC_MAX; ++c) {
        if (s + c * 64 >= e) break;
        L += Lpart[((size_t)c * N_NODES + n) * 4 + h];
        O += bf2f(Opart[((size_t)c * N_NODES + n) * 256 + tid]);
    }
    float o = (O / L) * att_n + x[(size_t)n * 256 + tid];
    // LayerNorm
    float s1 = o, s2 = o * o;
#pragma unroll
    for (int k2 = 32; k2; k2 >>= 1) {
        s1 += __shfl_xor(s1, k2);
        s2 += __shfl_xor(s2, k2);
    }
    __syncthreads();  // r1/r2 reuse
    if ((tid & 63) == 0) { r1[tid >> 6] = s1; r2[tid >> 6] = s2; }
    __syncthreads();
    float mu = (r1[0] + r1[1] + r1[2] + r1[3]) * (1.f / 256.f);
    float ms = (r2[0] + r2[1] + r2[2] + r2[3]) * (1.f / 256.f);
    float rs = rsqrtf(ms - mu * mu + LN_EPS);
    out[(size_t)n * 256 + tid] = (o - mu) * rs * gamma[tid] + beta[tid];
}

extern "C" void kernel_launch(void* const* d_in, const int* in_sizes, int n_in,
                              void* d_out, int out_size, void* d_ws, size_t ws_size,
                              hipStream_t stream) {
    const float* x     = (const float*)d_in[0];
    const float* Wq    = (const float*)d_in[1];
    const float* bq    = (const float*)d_in[2];
    const float* Wk    = (const float*)d_in[3];
    const float* bk    = (const float*)d_in[4];
    const float* Wv    = (const float*)d_in[5];
    const float* bv    = (const float*)d_in[6];
    const float* Wv1   = (const float*)d_in[7];
    const float* bv1   = (const float*)d_in[8];
    const float* Wv2   = (const float*)d_in[9];
    const float* bv2   = (const float*)d_in[10];
    const float* Wc1   = (const float*)d_in[11];
    const float* bc1   = (const float*)d_in[12];
    const float* Wc2   = (const float*)d_in[13];
    const float* bc2   = (const float*)d_in[14];
    const float* gamma = (const float*)d_in[15];
    const float* beta  = (const float*)d_in[16];
    const int*   batch = (const int*)d_in[17];

    float* out = (float*)d_out;        // [N, D]
    float* att = out + N_NODES * DIM;  // [N]

    // f32 region
    float* ws    = (float*)d_ws;
    float* Lpart = ws;                            // 6*4096*4
    float* gcw   = Lpart + KC_MAX * N_NODES * 4;  // 16*256
    float* w     = gcw + NG * DIM;                // 4096
    int*   seg   = (int*)(w + N_NODES);           // 17 ints, pad to 32
    // bf16 region (16B aligned)
    unsigned short* bws   = (unsigned short*)(w + N_NODES + 32);
    unsigned short* xb    = bws;                   // 4096*256
    unsigned short* Qb    = xb + N_NODES * DIM;    // 4160*256
    unsigned short* Kb    = Qb + RSLACK * DIM;     // 4160*256
    unsigned short* Vt    = Kb + RSLACK * DIM;     // 256*4160
    unsigned short* WqT   = Vt + DIM * RSLACK;     // 256*256
    unsigned short* WkT   = WqT + DIM * DIM;
    unsigned short* WvT   = WkT + DIM * DIM;
    unsigned short* Wv1T  = WvT + DIM * DIM;       // 128*256
    unsigned short* Wc1T  = Wv1T + 128 * DIM;      // 256*512
    unsigned short* Hvb   = Wc1T + DIM * 512;      // 4096*128
    unsigned short* Tb    = Hvb + N_NODES * 128;   // 4096*256
    unsigned short* Opart = Tb + N_NODES * DIM;    // 6*4096*256

    prep_kernel<<<1393, 256, 0, stream>>>(x, Wq, Wk, Wv, Wv1, Wc1, batch,
                                          xb, WqT, WkT, WvT, Wv1T, Wc1T, gcw, seg);
    gemm_kernel<<<dim3(64, 4, 5), 256, 0, stream>>>(xb, WqT, WkT, WvT, Wv1T, Wc1T,
                                                    bq, bk, bv, bv1, bc1, gcw, batch,
                                                    Qb, Kb, Vt, Tb, Hvb);
    attn_w_kernel<<<ATTN_BLOCKS + 1024, 256, 0, stream>>>(Qb, Kb, Vt, seg, Hvb, Tb,
                                                          Wv2, bv2, Wc2, bc2,
                                                          Opart, Lpart, w);
    combine_ln_kernel<<<N_NODES, 256, 0, stream>>>(Opart, Lpart, x, w, gamma, beta,
                                                   batch, seg, out, att);
}